// Round 7
// baseline (216.388 us; speedup 1.0000x reference)
//
#include <hip/hip_runtime.h>
#include <math.h>

// Problem constants
#define NBT 512
#define NF  256
#define NC  768
#define NROW 64
#define NORG 16
#define NE  128
#define SLD 260      // fp32 LDS row stride (16-row tiles)
#define SY  264      // bf16 LDS row stride for y (fallback kernel)
#define SYT 66       // bf16 col-major row stride (64 rows + 2 pad)

// ---- ws byte offsets ----
#define WS_SW_LAB1 0         // 256x256 bf16, 32-style frag order
#define WS_SW_ABN1 131072
#define WS_SW_ORG  1441792   // 256x256, 16-style
#define WS_SW_O2A  1572864
#define WS_SUMREL  1703936   // 16x768 f32 per-organ sums of lab_rel
#define WS_LAB_CB  1753088   // 128x256 f32 (bias folded)
#define WS_ABN_CB  1884160
#define WS_ADDSUM  2015232   // 16x256 f32: raw per-organ sums of rel@D
#define WS_WCNT    2031616   // 64x16 f32
#define WS_INVL    2035712
#define WS_INVA    2035776
#define WS_MASK    2035840
#define WS_SRTL    2035904   // 128 ints: (row<<24)|(org<<16)|e, organ-sorted ASC
#define WS_SRTA    2036544
// split-path raw per-(bt,side) organ sums: 512 x 16 x 256 f32 each
#define WS_RAWL    2097152
#define WS_RAWA    10485760
#define WS_NEED    18874368

typedef __attribute__((ext_vector_type(8)))  short bf16x8;
typedef __attribute__((ext_vector_type(16))) float f32x16;
typedef __attribute__((ext_vector_type(4)))  float f32x4;

__device__ __forceinline__ short f2bf(float f) {
    union { float f; unsigned u; } v; v.f = f;
    unsigned r = v.u + 0x7FFF + ((v.u >> 16) & 1);   // RNE
    return (short)(r >> 16);
}
__device__ __forceinline__ unsigned pack2bf(float f0, float f1) {
    union { float f; unsigned u; } a, b; a.f = f0; b.f = f1;
    unsigned r0 = a.u + 0x7FFF + ((a.u >> 16) & 1);
    unsigned r1 = b.u + 0x7FFF + ((b.u >> 16) & 1);
    return (r0 >> 16) | (r1 & 0xFFFF0000u);
}
__device__ __forceinline__ float bf2f(short s) {
    return __uint_as_float(((unsigned)(unsigned short)s) << 16);
}
__device__ __forceinline__ float tanh_fast(float x) {
    float xc = fminf(fmaxf(x, -15.f), 15.f);
    float e = __expf(2.f * xc);
    return 1.f - 2.f * __builtin_amdgcn_rcpf(e + 1.f);
}
__device__ __forceinline__ f32x16 mfma32(bf16x8 a, bf16x8 b, f32x16 c) {
    return __builtin_amdgcn_mfma_f32_32x32x16_bf16(a, b, c, 0, 0, 0);
}
__device__ __forceinline__ f32x4 mfma16(bf16x8 a, bf16x8 b, f32x4 c) {
    return __builtin_amdgcn_mfma_f32_16x16x32_bf16(a, b, c, 0, 0, 0);
}
__device__ __forceinline__ bf16x8 pack_a16(const float* __restrict__ p) {
    float4 x0 = *(const float4*)p;
    float4 x1 = *(const float4*)(p + 4);
    union { bf16x8 v; unsigned u[4]; } r;
    r.u[0] = __builtin_amdgcn_perm(__float_as_uint(x0.y), __float_as_uint(x0.x), 0x07060302);
    r.u[1] = __builtin_amdgcn_perm(__float_as_uint(x0.w), __float_as_uint(x0.z), 0x07060302);
    r.u[2] = __builtin_amdgcn_perm(__float_as_uint(x1.y), __float_as_uint(x1.x), 0x07060302);
    r.u[3] = __builtin_amdgcn_perm(__float_as_uint(x1.w), __float_as_uint(x1.z), 0x07060302);
    return r.v;
}

// ---------------------------------------------------------------------------
// pk_pre2: single pre-kernel, 241 blocks, longest-first:
//   0..63    cb tables (B read on-the-fly from global W)
//   64..111  sumRel
//   112      metadata (counts, sorted edge lists, wcnt)
//   113..240 weight swizzles (LAB1, ABN1, ORG, O2A)
// ---------------------------------------------------------------------------
__device__ __forceinline__ void swz32(const float* __restrict__ src, short* __restrict__ dst, int s) {
    const int l = s & 63, rest = s >> 6;
    const int nt = rest & 7, k16 = rest >> 3;
    const int n = nt * 32 + (l & 31);
    const int kb = k16 * 16 + ((l >> 5) & 1) * 8;
    bf16x8 v;
    #pragma unroll
    for (int j = 0; j < 8; ++j) v[j] = f2bf(src[(kb + j) * NF + n]);
    *(bf16x8*)(dst + s * 8) = v;
}
__device__ __forceinline__ void swz16(const float* __restrict__ src, short* __restrict__ dst, int s) {
    const int l = s & 63, rest = s >> 6;
    const int nt = rest & 15, k32 = rest >> 4;
    const int n = nt * 16 + (l & 15);
    const int kb = k32 * 32 + ((l >> 4) & 3) * 8;
    bf16x8 v;
    #pragma unroll
    for (int j = 0; j < 8; ++j) v[j] = f2bf(src[(kb + j) * NF + n]);
    *(bf16x8*)(dst + s * 8) = v;
}

__global__ __launch_bounds__(256) void pk_pre2(
    const float* __restrict__ W_lab, const float* __restrict__ W_abn,
    const float* __restrict__ W_org,
    const float* __restrict__ W_o2a, const float* __restrict__ lab_rel,
    const float* __restrict__ lab_con, const float* __restrict__ abn_con,
    const float* __restrict__ abn_rel,
    const float* __restrict__ b_lab, const float* __restrict__ b_abn,
    const int* __restrict__ lab_idx, const int* __restrict__ lab_org_idx,
    const int* __restrict__ abn_idx, const int* __restrict__ abn_org_idx,
    const int* __restrict__ o2a_abn_idx, const int* __restrict__ o2a_org_idx,
    char* __restrict__ ws) {
    __shared__ __align__(16) float sP[4 * 1024];     // cb blocks only (16 KB)
    const int bid = blockIdx.x;
    if (bid < 64) {
        // ---- cb tables: (con[idx]+rel) @ W2 + bias.  B read on-the-fly. ----
        const int tid = threadIdx.x, l = tid & 63, w = tid >> 6;
        const int side = bid >> 5;                   // 0 lab, 1 abn
        const int b2 = bid & 31;
        const int mq = b2 >> 3, nb = b2 & 7;         // 4 m-tiles x 8 n-tiles
        const int em = mq * 32;
        const float* W2  = side ? (W_abn + NF * NF) : (W_lab + NF * NF);
        const float* con = side ? abn_con : lab_con;
        const float* rel = side ? abn_rel : lab_rel;
        const int*   idx = side ? abn_idx : lab_idx;

        f32x16 acc;
        #pragma unroll
        for (int r = 0; r < 16; ++r) acc[r] = 0.f;

        const int e  = em + (l & 31);
        const int kk = ((l >> 5) & 1) * 8;
        const int n  = nb * 32 + (l & 31);
        const float* cp = con + idx[e] * NC;
        const float* rp = rel + e * NC;
        #pragma unroll 4
        for (int k16 = 0; k16 < 12; ++k16) {
            const int k = (w * 12 + k16) * 16 + kk;  // global K offset (incl lane half)
            float4 c0 = *(const float4*)(cp + k);
            float4 c1 = *(const float4*)(cp + k + 4);
            float4 r0 = *(const float4*)(rp + k);
            float4 r1 = *(const float4*)(rp + k + 4);
            float v[8] = {c0.x + r0.x, c0.y + r0.y, c0.z + r0.z, c0.w + r0.w,
                          c1.x + r1.x, c1.y + r1.y, c1.z + r1.z, c1.w + r1.w};
            bf16x8 af;
            #pragma unroll
            for (int j = 0; j < 8; ++j) af[j] = f2bf(v[j]);
            const float* wp = W2 + k * NF + n;       // B col n, rows k..k+7
            bf16x8 bv;
            #pragma unroll
            for (int j = 0; j < 8; ++j) bv[j] = f2bf(wp[j * NF]);
            acc = mfma32(af, bv, acc);
        }
        #pragma unroll
        for (int r = 0; r < 16; ++r) sP[w * 1024 + r * 64 + l] = acc[r];
        __syncthreads();
        float* outp = (float*)(ws + (side ? WS_ABN_CB : WS_LAB_CB));
        const float* bias = side ? b_abn : b_lab;
        #pragma unroll
        for (int q = 0; q < 4; ++q) {
            const int idx2 = q * 256 + tid;
            float v = sP[idx2] + sP[1024 + idx2] + sP[2048 + idx2] + sP[3072 + idx2];
            const int reg = idx2 >> 6, ll = idx2 & 63;
            const int er = (reg & 3) + 8 * (reg >> 2) + 4 * (ll >> 5);
            const int col = nb * 32 + (ll & 31);
            outp[(em + er) * NF + col] = v + bias[col];
        }
    } else if (bid < 112) {
        // ---- sumRel[o][k] = sum over lab edges with org==o of lab_rel[e][k] ----
        const int b2 = bid - 64;
        const int o = b2 / 3, kth = b2 % 3;
        const int k = kth * 256 + threadIdx.x;
        float s = 0.f;
        #pragma unroll 16
        for (int e = 0; e < NE; ++e) {
            const float v = lab_rel[e * NC + k];
            s += (lab_org_idx[e] == o) ? v : 0.f;
        }
        ((float*)(ws + WS_SUMREL))[o * NC + k] = s;
    } else if (bid == 112) {
        // ---- metadata: counts, organ-sorted edge lists, wcnt ----
        __shared__ int cL[NORG], cA[NORG], cC[NROW * NORG];
        __shared__ int goL[NORG + 1], goA[NORG + 1], curL[NORG], curA[NORG];
        const int t = threadIdx.x;
        for (int i = t; i < NROW * NORG; i += 256) cC[i] = 0;
        if (t < NORG) { cL[t] = 0; cA[t] = 0; }
        __syncthreads();
        if (t < NE) {
            atomicAdd(&cL[lab_org_idx[t]], 1);
            atomicAdd(&cA[abn_org_idx[t]], 1);
            atomicAdd(&cC[o2a_abn_idx[t] * NORG + o2a_org_idx[t]], 1);
        }
        __syncthreads();
        if (t == 0) { int s = 0; for (int o = 0; o < NORG; ++o) { goL[o] = s; s += cL[o]; } goL[NORG] = s; }
        if (t == 1) { int s = 0; for (int o = 0; o < NORG; ++o) { goA[o] = s; s += cA[o]; } goA[NORG] = s; }
        __syncthreads();
        if (t < NORG) { curL[t] = goL[t]; curA[t] = goA[t]; }
        __syncthreads();
        if (t < NE) {
            const int ol = lab_org_idx[t], oa = abn_org_idx[t];
            int p = atomicAdd(&curL[ol], 1);
            ((int*)(ws + WS_SRTL))[p] = (lab_idx[t] << 24) | (ol << 16) | t;
            int q = atomicAdd(&curA[oa], 1);
            ((int*)(ws + WS_SRTA))[q] = (abn_idx[t] << 24) | (oa << 16) | t;
        }
        if (t < NORG) {
            ((float*)(ws + WS_INVL))[t] = cL[t] ? 1.f / (float)cL[t] : 0.f;
            ((float*)(ws + WS_INVA))[t] = cA[t] ? 1.f / (float)cA[t] : 0.f;
            ((float*)(ws + WS_MASK))[t] = (cL[t] || cA[t]) ? 1.f : 0.f;
        }
        if (t < NROW) {
            int dega = 0;
            for (int o = 0; o < NORG; ++o) dega += cC[t * NORG + o];
            float inv = 1.f / (float)(dega > 1 ? dega : 1);
            for (int o = 0; o < NORG; ++o)
                ((float*)(ws + WS_WCNT))[t * NORG + o] = (float)cC[t * NORG + o] * inv;
        }
    } else {
        const int gid = (bid - 113) * 256 + threadIdx.x;
        if      (gid <  8192) swz32(W_lab, (short*)(ws + WS_SW_LAB1), gid);
        else if (gid < 16384) swz32(W_abn, (short*)(ws + WS_SW_ABN1), gid - 8192);
        else if (gid < 24576) swz16(W_org, (short*)(ws + WS_SW_ORG),  gid - 16384);
        else                  swz16(W_o2a, (short*)(ws + WS_SW_O2A),  gid - 24576);
    }
}

// ---------------------------------------------------------------------------
// Shared helpers.
// ---------------------------------------------------------------------------
__device__ __forceinline__ void stage_A(const float* __restrict__ X, short* __restrict__ sA, int tid) {
    #pragma unroll
    for (int ss = 0; ss < 8; ++ss) {
        const int s = tid + 256 * ss;
        const int k16 = s >> 7, rt = (s >> 6) & 1, l = s & 63;
        const int row = rt * 32 + (l & 31);
        const int kb = k16 * 16 + ((l >> 5) & 1) * 8;
        *(bf16x8*)(sA + s * 8) = pack_a16(X + row * NF + kb);
    }
}

template <int POST>   // 0: tanh * mask ; 1: plain
__device__ __forceinline__ void gemm_small(
    const float* __restrict__ sIn, const short* __restrict__ Bsw,
    const float* __restrict__ bias, const float* __restrict__ mask,
    float* __restrict__ sOut, int tid) {
    const int l = tid & 63, w = tid >> 6;
    f32x4 acc[4];
    #pragma unroll
    for (int i = 0; i < 4; ++i) { acc[i][0] = 0.f; acc[i][1] = 0.f; acc[i][2] = 0.f; acc[i][3] = 0.f; }
    #pragma unroll 2
    for (int k32 = 0; k32 < 8; ++k32) {
        const float* ap = sIn + (l & 15) * SLD + k32 * 32 + ((l >> 4) & 3) * 8;
        bf16x8 af = pack_a16(ap);
        #pragma unroll
        for (int nt = 0; nt < 4; ++nt) {
            bf16x8 bfv = *(const bf16x8*)(Bsw + ((k32 * 16 + w * 4 + nt) * 64 + l) * 8);
            acc[nt] = mfma16(af, bfv, acc[nt]);
        }
    }
    #pragma unroll
    for (int nt = 0; nt < 4; ++nt) {
        const int col = w * 64 + nt * 16 + (l & 15);
        const float b = bias[col];
        #pragma unroll
        for (int reg = 0; reg < 4; ++reg) {
            const int row = ((l >> 4) & 3) * 4 + reg;
            float v = acc[nt][reg] + b;
            if (POST == 0) v = tanh_fast(v) * mask[row];
            sOut[row * SLD + col] = v;
        }
    }
}

// ---------------------------------------------------------------------------
// addsum body: (16-row A = sumRel, zero-padded to 32) @ D -> WS_ADDSUM raw.
// B read on-the-fly from global D. nb in [0,8). Needs 16 KB scratch (sP).
// ---------------------------------------------------------------------------
__device__ __forceinline__ void addsum_body(const float* __restrict__ D,
                                            char* __restrict__ ws, float* __restrict__ sP,
                                            int nb, int tid) {
    const int l = tid & 63, w = tid >> 6;
    const float* sr = (const float*)(ws + WS_SUMREL);
    f32x16 acc;
    #pragma unroll
    for (int r = 0; r < 16; ++r) acc[r] = 0.f;
    const int row = l & 31;
    const int kk = ((l >> 5) & 1) * 8;
    const int n = nb * 32 + (l & 31);
    const float* cp = sr + row * NC;
    #pragma unroll 4
    for (int k16 = 0; k16 < 12; ++k16) {
        const int k = w * 192 + k16 * 16 + kk;
        bf16x8 af;
        if (row < NORG) {
            af = pack_a16(cp + k);
        } else {
            #pragma unroll
            for (int j = 0; j < 8; ++j) af[j] = 0;
        }
        const float* dp = D + k * NF + n;
        bf16x8 bv;
        #pragma unroll
        for (int j = 0; j < 8; ++j) bv[j] = f2bf(dp[j * NF]);
        acc = mfma32(af, bv, acc);
    }
    #pragma unroll
    for (int r = 0; r < 16; ++r) sP[w * 1024 + r * 64 + l] = acc[r];
    __syncthreads();
    float* outp = (float*)(ws + WS_ADDSUM);
    #pragma unroll
    for (int q = 0; q < 4; ++q) {
        const int idx2 = q * 256 + tid;
        float v = sP[idx2] + sP[1024 + idx2] + sP[2048 + idx2] + sP[3072 + idx2];
        const int reg = idx2 >> 6, ll = idx2 & 63;
        const int er = (reg & 3) + 8 * (reg >> 2) + 4 * (ll >> 5);
        const int col = nb * 32 + (ll & 31);
        if (er < NORG) outp[er * NF + col] = v;
    }
}

// ---------------------------------------------------------------------------
// kg_side v2: blocks 0..7 addsum riders; blocks 8..2055: one per
// (bt, side, N-half). LDS union (A half-K stage / Y^T 128x66) = 16.9 KB ->
// 8 blocks/CU possible (LDS-limited). launch_bounds min kept at 4 so the
// register allocator is NOT forced to spill; natural VGPR use should allow 8.
// Edge loop: 128 cols x 2 edge-sublists per block; sorted-contiguous organ
// runs overlap in <=1 boundary organ, combined via LDS after a barrier.
// ---------------------------------------------------------------------------
__global__ __launch_bounds__(256, 4) void kg_side(
    const float* __restrict__ lab_feats, const float* __restrict__ abn_feats,
    const float* __restrict__ D, char* __restrict__ ws) {
    __shared__ __align__(16) short sBuf[128 * SYT];  // 16896 B: A-stage / Y^T
    __shared__ int sE[NE];
    __shared__ float sOv[2 * 128];

    const int tid = threadIdx.x;
    if (blockIdx.x < 8) {                            // addsum rider blocks
        addsum_body(D, ws, (float*)sBuf, blockIdx.x, tid);
        return;
    }
    const int idx = blockIdx.x - 8;
    const int h    = idx & 1;                        // N-half (cols h*128..+127)
    const int side = (idx >> 1) & 1;                 // 0 = lab, 1 = abn
    const int bt   = idx >> 2;

    if (tid < NE) sE[tid] = ((const int*)(ws + (side ? WS_SRTA : WS_SRTL)))[tid];

    const float* X   = (side ? abn_feats : lab_feats) + bt * (NROW * NF);
    const short* Bsw = (const short*)(ws + (side ? WS_SW_ABN1 : WS_SW_LAB1));
    const float* cb  = (const float*)(ws + (side ? WS_ABN_CB : WS_LAB_CB));
    float* rawo = (float*)(ws + (side ? WS_RAWA : WS_RAWL)) + bt * (NORG * NF);

    const int l = tid & 63, w = tid >> 6;
    f32x16 acc[2];
    #pragma unroll
    for (int i = 0; i < 2; ++i)
        #pragma unroll
        for (int r = 0; r < 16; ++r) acc[i][r] = 0.f;

    // two K-halves staged into the same 16 KB region
    #pragma unroll
    for (int kc = 0; kc < 2; ++kc) {
        __syncthreads();                             // prior A reads done
        #pragma unroll
        for (int ss = 0; ss < 4; ++ss) {
            const int s = tid + 256 * ss;            // 0..1023
            const int k16l = s >> 7, rt = (s >> 6) & 1, ll = s & 63;
            const int row = rt * 32 + (ll & 31);
            const int kb = (kc * 8 + k16l) * 16 + ((ll >> 5) & 1) * 8;
            *(bf16x8*)(sBuf + s * 8) = pack_a16(X + row * NF + kb);
        }
        __syncthreads();
        #pragma unroll
        for (int k16l = 0; k16l < 8; ++k16l) {
            const int k16 = kc * 8 + k16l;
            bf16x8 a0 = *(const bf16x8*)(sBuf + ((k16l * 2 + 0) * 64 + l) * 8);
            bf16x8 a1 = *(const bf16x8*)(sBuf + ((k16l * 2 + 1) * 64 + l) * 8);
            bf16x8 b0 = *(const bf16x8*)(Bsw + (((k16 * 8) + h * 4 + w) * 64 + l) * 8);
            acc[0] = mfma32(a0, b0, acc[0]);
            acc[1] = mfma32(a1, b0, acc[1]);
        }
    }
    __syncthreads();                                 // A reads done; region = Y^T

    // col-major writeback: local col c = w*32 + (l&31); regs 4q..4q+3 = rows
    {
        const int c = w * 32 + (l & 31);
        #pragma unroll
        for (int rt = 0; rt < 2; ++rt)
            #pragma unroll
            for (int q = 0; q < 4; ++q) {
                const int rowb = rt * 32 + 8 * q + 4 * (l >> 5);
                unsigned u0 = pack2bf(acc[rt][4 * q + 0], acc[rt][4 * q + 1]);
                unsigned u1 = pack2bf(acc[rt][4 * q + 2], acc[rt][4 * q + 3]);
                *(unsigned*)(sBuf + c * SYT + rowb)     = u0;
                *(unsigned*)(sBuf + c * SYT + rowb + 2) = u1;
            }
    }
    __syncthreads();

    // edge reduction: thread = (edge-half eh, local col cl); 64 edges each.
    const int eh = tid >> 7;
    const int cl = tid & 127;
    const int gc = h * 128 + cl;
    const short* yc = sBuf + cl * SYT;
    const float* cbt = cb + gc;
    const int ob0 = (__builtin_amdgcn_readfirstlane(sE[63]) >> 16) & 255;
    const int ob1 = (__builtin_amdgcn_readfirstlane(sE[64]) >> 16) & 255;
    const bool bshared = (ob0 == ob1);               // organ run crosses e63/e64
    const int ebase = eh * 64;
    float racc = 0.f;
    int curo = (__builtin_amdgcn_readfirstlane(sE[ebase]) >> 16) & 255;
    for (int i0 = 0; i0 < 64; i0 += 8) {
        int   pk8[8];
        float cb8[8], y8[8];
        #pragma unroll
        for (int j = 0; j < 8; ++j) {
            const int pk = __builtin_amdgcn_readfirstlane(sE[ebase + i0 + j]);
            pk8[j] = pk;
            cb8[j] = cbt[(pk & 0xffff) * NF];
            y8[j]  = bf2f(yc[pk >> 24]);
        }
        #pragma unroll
        for (int j = 0; j < 8; ++j) {
            const int o = (pk8[j] >> 16) & 255;
            if (o != curo) {             // wave-uniform branch
                if (bshared && curo == ob0) sOv[eh * 128 + cl] = racc;
                else rawo[curo * NF + gc] = racc;
                racc = 0.f; curo = o;
            }
            racc += tanh_fast(y8[j] + cb8[j]);
        }
    }
    if (bshared && curo == ob0) sOv[eh * 128 + cl] = racc;
    else rawo[curo * NF + gc] = racc;

    if (bshared) {                       // block-uniform
        __syncthreads();
        if (tid < 128) rawo[ob0 * NF + h * 128 + tid] = sOv[tid] + sOv[128 + tid];
    }
}

// ---------------------------------------------------------------------------
// kg_back: combine means, organ GEMMs, output add. 512 blocks.
// ---------------------------------------------------------------------------
__global__ __launch_bounds__(256, 4) void kg_back(
    const float* __restrict__ abn_feats, const float* __restrict__ b_org,
    const float* __restrict__ b_o2a, const char* __restrict__ ws,
    float* __restrict__ out) {
    __shared__ __align__(16) float sIn[NORG * SLD];  // 16640 B
    __shared__ __align__(16) float sSt[NORG * SLD];  // 16640 B
    __shared__ float sWc[NROW * NORG];               // 4096 B
    __shared__ float sInvL[NORG], sInvA[NORG], sMsk[NORG];

    const int tid = threadIdx.x;
    const int bt = blockIdx.x;

    if      (tid < NORG)     sInvL[tid]          = ((const float*)(ws + WS_INVL))[tid];
    else if (tid < 2 * NORG) sInvA[tid - NORG]   = ((const float*)(ws + WS_INVA))[tid - NORG];
    else if (tid < 3 * NORG) sMsk[tid - 2 * NORG] = ((const float*)(ws + WS_MASK))[tid - 2 * NORG];
    #pragma unroll
    for (int i = tid; i < NROW * NORG; i += 256)
        sWc[i] = ((const float*)(ws + WS_WCNT))[i];

    const float* rawL = (const float*)(ws + WS_RAWL) + bt * (NORG * NF);
    const float* rawA = (const float*)(ws + WS_RAWA) + bt * (NORG * NF);
    const float* addR = (const float*)(ws + WS_ADDSUM);
    __syncthreads();

    // sIn[o][g] = (rawL+addR)*invL + rawA*invA  (selects guard unwritten organs)
    const int g = tid;
    #pragma unroll
    for (int o = 0; o < NORG; ++o) {
        const float il = sInvL[o], ia = sInvA[o];
        const float vl = (il > 0.f) ? (rawL[o * NF + g] + addR[o * NF + g]) * il : 0.f;
        const float va = (ia > 0.f) ? rawA[o * NF + g] * ia : 0.f;
        sIn[o * SLD + g] = vl + va;
    }
    __syncthreads();

    gemm_small<0>(sIn, (const short*)(ws + WS_SW_ORG), b_org, sMsk, sSt, tid);
    __syncthreads();
    gemm_small<1>(sSt, (const short*)(ws + WS_SW_O2A), b_o2a, nullptr, sIn, tid);
    __syncthreads();

    // out[a][g] = abn_feats[a][g] + sum_o wcnt[a][o]*msg[o][g]
    float mr[NORG];
    #pragma unroll
    for (int o = 0; o < NORG; ++o) mr[o] = sIn[o * SLD + g];
    const float* src = abn_feats + bt * (NROW * NF);
    float* dst = out + bt * (NROW * NF);
    #pragma unroll 8
    for (int a = 0; a < NROW; ++a) {
        float s = src[a * NF + g];
        #pragma unroll
        for (int o = 0; o < NORG; ++o) s += sWc[a * NORG + o] * mr[o];
        dst[a * NF + g] = s;
    }
}

// ---------------------------------------------------------------------------
// Fallback path (ws too small): standalone addsum + single-kernel main.
// ---------------------------------------------------------------------------
__global__ __launch_bounds__(256) void pk_addsum(const float* __restrict__ D,
                                                 char* __restrict__ ws) {
    __shared__ __align__(16) float sP[4 * 1024];
    addsum_body(D, ws, sP, blockIdx.x, threadIdx.x);
}

template <bool LAB>
__device__ __forceinline__ void side_pass(
    const float* __restrict__ X, const short* __restrict__ Bsw,
    const float* __restrict__ cb, const float* __restrict__ addR,
    const float* __restrict__ sInv, const int* __restrict__ sE,
    short* __restrict__ sA, float* __restrict__ sAcc, int tid) {
    __syncthreads();                 // prior users of region done
    stage_A(X, sA, tid);
    __syncthreads();
    const int l = tid & 63, w = tid >> 6;
    f32x16 acc[2][2];
    #pragma unroll
    for (int i = 0; i < 2; ++i)
        #pragma unroll
        for (int j = 0; j < 2; ++j)
            #pragma unroll
            for (int r = 0; r < 16; ++r) acc[i][j][r] = 0.f;
    #pragma unroll 8
    for (int k16 = 0; k16 < 16; ++k16) {
        bf16x8 a0 = *(const bf16x8*)(sA + ((k16 * 2 + 0) * 64 + l) * 8);
        bf16x8 a1 = *(const bf16x8*)(sA + ((k16 * 2 + 1) * 64 + l) * 8);
        bf16x8 b0 = *(const bf16x8*)(Bsw + ((k16 * 8 + 2 * w + 0) * 64 + l) * 8);
        bf16x8 b1 = *(const bf16x8*)(Bsw + ((k16 * 8 + 2 * w + 1) * 64 + l) * 8);
        acc[0][0] = mfma32(a0, b0, acc[0][0]);
        acc[1][0] = mfma32(a1, b0, acc[1][0]);
        acc[0][1] = mfma32(a0, b1, acc[0][1]);
        acc[1][1] = mfma32(a1, b1, acc[1][1]);
    }
    __syncthreads();                 // all sA reads done; region becomes sY
    short* sYs = sA;
    #pragma unroll
    for (int rt = 0; rt < 2; ++rt)
        #pragma unroll
        for (int nt = 0; nt < 2; ++nt) {
            const int col = w * 64 + nt * 32 + (l & 31);
            #pragma unroll
            for (int reg = 0; reg < 16; ++reg) {
                const int row = rt * 32 + (reg & 3) + 8 * (reg >> 2) + 4 * (l >> 5);
                sYs[row * SY + col] = f2bf(acc[rt][nt][reg]);
            }
        }
    __syncthreads();
    const int t = tid;
    if (LAB) {
        #pragma unroll
        for (int o = 0; o < NORG; ++o)
            sAcc[o * SLD + t] = addR[o * NF + t] * sInv[o];
    }
    float racc = 0.f;
    int curo = (sE[0] >> 16) & 255;
    #pragma unroll 4
    for (int i = 0; i < NE; ++i) {
        const int pk = sE[i];
        const int o = (pk >> 16) & 255;
        if (o != curo) {             // wave-uniform branch
            sAcc[curo * SLD + t] += racc * sInv[curo];
            racc = 0.f; curo = o;
        }
        const float yv = bf2f(sYs[(pk >> 24) * SY + t]);
        racc += tanh_fast(yv + cb[(pk & 0xffff) * NF + t]);
    }
    sAcc[curo * SLD + t] += racc * sInv[curo];
}

__global__ __launch_bounds__(256, 2) void kg_main(
    const float* __restrict__ lab_feats, const float* __restrict__ abn_feats,
    const float* __restrict__ b_org, const float* __restrict__ b_o2a,
    const char* __restrict__ ws, float* __restrict__ out) {
    __shared__ __align__(16) short sY[NROW * SY];        // 33792 B; aliases A-frags
    __shared__ __align__(16) float sAcc[NORG * SLD];     // 16640 B; later sMsg
    __shared__ __align__(16) float sSt [NORG * SLD];     // 16640 B
    __shared__ int   sEL[NE], sEA[NE];
    __shared__ float sInvL[NORG], sInvA[NORG], sMsk[NORG];

    const int tid = threadIdx.x;
    const int bt = blockIdx.x;

    if (tid < NE) {
        sEL[tid] = ((const int*)(ws + WS_SRTL))[tid];
        sEA[tid] = ((const int*)(ws + WS_SRTA))[tid];
    } else {
        const int u = tid - NE;
        if      (u < 16) sInvL[u]      = ((const float*)(ws + WS_INVL))[u];
        else if (u < 32) sInvA[u - 16] = ((const float*)(ws + WS_INVA))[u - 16];
        else if (u < 48) sMsk[u - 32]  = ((const float*)(ws + WS_MASK))[u - 32];
    }

    const float* Xl = lab_feats + bt * (NROW * NF);
    const float* Xa = abn_feats + bt * (NROW * NF);
    side_pass<true >(Xl, (const short*)(ws + WS_SW_LAB1),
                     (const float*)(ws + WS_LAB_CB), (const float*)(ws + WS_ADDSUM),
                     sInvL, sEL, sY, sAcc, tid);
    side_pass<false>(Xa, (const short*)(ws + WS_SW_ABN1),
                     (const float*)(ws + WS_ABN_CB), nullptr,
                     sInvA, sEA, sY, sAcc, tid);
    __syncthreads();

    gemm_small<0>(sAcc, (const short*)(ws + WS_SW_ORG), b_org, sMsk, sSt, tid);
    __syncthreads();
    float* sMsg = sAcc;   // alias (input of <1> is sSt)
    gemm_small<1>(sSt, (const short*)(ws + WS_SW_O2A), b_o2a, nullptr, sMsg, tid);
    __syncthreads();

    {
        const int g = tid;
        float mr[NORG];
        #pragma unroll
        for (int o = 0; o < NORG; ++o) mr[o] = sMsg[o * SLD + g];
        const float* src = abn_feats + bt * (NROW * NF);
        float* dst = out + bt * (NROW * NF);
        const float* wc = (const float*)(ws + WS_WCNT);
        #pragma unroll 4
        for (int a = 0; a < NROW; ++a) {
            float s = src[a * NF + g];
            #pragma unroll
            for (int o = 0; o < NORG; ++o) s += wc[a * NORG + o] * mr[o];
            dst[a * NF + g] = s;
        }
    }
}

// ---------------------------------------------------------------------------
extern "C" void kernel_launch(void* const* d_in, const int* in_sizes, int n_in,
                              void* d_out, int out_size, void* d_ws, size_t ws_size,
                              hipStream_t stream) {
    const float* lab_feats   = (const float*)d_in[0];
    const float* abn_feats   = (const float*)d_in[1];
    const float* lab_concept = (const float*)d_in[2];
    const float* abn_concept = (const float*)d_in[3];
    const float* lab_rel     = (const float*)d_in[4];
    const float* abn_rel     = (const float*)d_in[5];
    const float* W_lab       = (const float*)d_in[6];
    const float* b_lab       = (const float*)d_in[7];
    const float* W_abn       = (const float*)d_in[8];
    const float* b_abn       = (const float*)d_in[9];
    const float* W_org       = (const float*)d_in[10];
    const float* b_org       = (const float*)d_in[11];
    const float* D           = (const float*)d_in[12];
    const float* W_o2a       = (const float*)d_in[13];
    const float* b_o2a       = (const float*)d_in[14];
    const int* lab_idx     = (const int*)d_in[16];
    const int* lab_org_idx = (const int*)d_in[17];
    const int* abn_idx     = (const int*)d_in[18];
    const int* abn_org_idx = (const int*)d_in[19];
    const int* o2a_abn_idx = (const int*)d_in[20];
    const int* o2a_org_idx = (const int*)d_in[21];
    char* ws = (char*)d_ws;
    float* out = (float*)d_out;

    pk_pre2<<<241, 256, 0, stream>>>(W_lab, W_abn, W_org, W_o2a, lab_rel,
                                     lab_concept, abn_concept, abn_rel,
                                     b_lab, b_abn,
                                     lab_idx, lab_org_idx, abn_idx, abn_org_idx,
                                     o2a_abn_idx, o2a_org_idx, ws);
    if (ws_size >= (size_t)WS_NEED) {
        kg_side<<<8 + 4 * NBT, 256, 0, stream>>>(lab_feats, abn_feats, D, ws);
        kg_back<<<NBT, 256, 0, stream>>>(abn_feats, b_org, b_o2a, ws, out);
    } else {
        pk_addsum<<<8, 256, 0, stream>>>(D, ws);
        kg_main<<<NBT, 256, 0, stream>>>(lab_feats, abn_feats, b_org, b_o2a, ws, out);
    }
}

// Round 8
// 210.419 us; speedup vs baseline: 1.0284x; 1.0284x over previous
//
#include <hip/hip_runtime.h>
#include <math.h>

// Problem constants
#define NBT 512
#define NF  256
#define NC  768
#define NROW 64
#define NORG 16
#define NE  128
#define SLD 260      // fp32 LDS row stride (16-row tiles)
#define SY  264      // bf16 LDS row stride for y

// ---- ws byte offsets ----
#define WS_SW_LAB1 0         // 256x256 bf16, 32-style frag order
#define WS_SW_ABN1 131072
#define WS_SW_ORG  1441792   // 256x256, 16-style
#define WS_SW_O2A  1572864
#define WS_SUMREL  1703936   // 16x768 f32 per-organ sums of lab_rel
#define WS_LAB_CB  1753088   // 128x256 f32 (bias folded)
#define WS_ABN_CB  1884160
#define WS_ADDSUM  2015232   // 16x256 f32: raw per-organ sums of rel@D
#define WS_WCNT    2031616   // 64x16 f32
#define WS_INVL    2035712
#define WS_INVA    2035776
#define WS_MASK    2035840
#define WS_SRTL    2035904   // 128 ints: (row<<24)|(org<<16)|e, organ-sorted ASC
#define WS_SRTA    2036544
// split-path raw per-(bt,side) organ sums: 512 x 16 x 256 f32 each
#define WS_RAWL    2097152
#define WS_RAWA    10485760
#define WS_NEED    18874368

typedef __attribute__((ext_vector_type(8)))  short bf16x8;
typedef __attribute__((ext_vector_type(16))) float f32x16;
typedef __attribute__((ext_vector_type(4)))  float f32x4;

__device__ __forceinline__ short f2bf(float f) {
    union { float f; unsigned u; } v; v.f = f;
    unsigned r = v.u + 0x7FFF + ((v.u >> 16) & 1);   // RNE
    return (short)(r >> 16);
}
__device__ __forceinline__ float bf2f(short s) {
    return __uint_as_float(((unsigned)(unsigned short)s) << 16);
}
__device__ __forceinline__ float tanh_fast(float x) {
    float xc = fminf(fmaxf(x, -15.f), 15.f);
    float e = __expf(2.f * xc);
    return 1.f - 2.f * __builtin_amdgcn_rcpf(e + 1.f);
}
__device__ __forceinline__ f32x16 mfma32(bf16x8 a, bf16x8 b, f32x16 c) {
    return __builtin_amdgcn_mfma_f32_32x32x16_bf16(a, b, c, 0, 0, 0);
}
__device__ __forceinline__ f32x4 mfma16(bf16x8 a, bf16x8 b, f32x4 c) {
    return __builtin_amdgcn_mfma_f32_16x16x32_bf16(a, b, c, 0, 0, 0);
}
__device__ __forceinline__ bf16x8 pack_a16(const float* __restrict__ p) {
    float4 x0 = *(const float4*)p;
    float4 x1 = *(const float4*)(p + 4);
    union { bf16x8 v; unsigned u[4]; } r;
    r.u[0] = __builtin_amdgcn_perm(__float_as_uint(x0.y), __float_as_uint(x0.x), 0x07060302);
    r.u[1] = __builtin_amdgcn_perm(__float_as_uint(x0.w), __float_as_uint(x0.z), 0x07060302);
    r.u[2] = __builtin_amdgcn_perm(__float_as_uint(x1.y), __float_as_uint(x1.x), 0x07060302);
    r.u[3] = __builtin_amdgcn_perm(__float_as_uint(x1.w), __float_as_uint(x1.z), 0x07060302);
    return r.v;
}

// ---------------------------------------------------------------------------
// pk_pre2: single pre-kernel, 241 blocks, longest-first:
//   0..63    cb tables (B read on-the-fly from global W)
//   64..111  sumRel
//   112      metadata (counts, sorted edge lists, wcnt)
//   113..240 weight swizzles (LAB1, ABN1, ORG, O2A)
// ---------------------------------------------------------------------------
__device__ __forceinline__ void swz32(const float* __restrict__ src, short* __restrict__ dst, int s) {
    const int l = s & 63, rest = s >> 6;
    const int nt = rest & 7, k16 = rest >> 3;
    const int n = nt * 32 + (l & 31);
    const int kb = k16 * 16 + ((l >> 5) & 1) * 8;
    bf16x8 v;
    #pragma unroll
    for (int j = 0; j < 8; ++j) v[j] = f2bf(src[(kb + j) * NF + n]);
    *(bf16x8*)(dst + s * 8) = v;
}
__device__ __forceinline__ void swz16(const float* __restrict__ src, short* __restrict__ dst, int s) {
    const int l = s & 63, rest = s >> 6;
    const int nt = rest & 15, k32 = rest >> 4;
    const int n = nt * 16 + (l & 15);
    const int kb = k32 * 32 + ((l >> 4) & 3) * 8;
    bf16x8 v;
    #pragma unroll
    for (int j = 0; j < 8; ++j) v[j] = f2bf(src[(kb + j) * NF + n]);
    *(bf16x8*)(dst + s * 8) = v;
}

__global__ __launch_bounds__(256) void pk_pre2(
    const float* __restrict__ W_lab, const float* __restrict__ W_abn,
    const float* __restrict__ W_org,
    const float* __restrict__ W_o2a, const float* __restrict__ lab_rel,
    const float* __restrict__ lab_con, const float* __restrict__ abn_con,
    const float* __restrict__ abn_rel,
    const float* __restrict__ b_lab, const float* __restrict__ b_abn,
    const int* __restrict__ lab_idx, const int* __restrict__ lab_org_idx,
    const int* __restrict__ abn_idx, const int* __restrict__ abn_org_idx,
    const int* __restrict__ o2a_abn_idx, const int* __restrict__ o2a_org_idx,
    char* __restrict__ ws) {
    __shared__ __align__(16) float sP[4 * 1024];     // cb blocks only (16 KB)
    const int bid = blockIdx.x;
    if (bid < 64) {
        // ---- cb tables: (con[idx]+rel) @ W2 + bias.  B read on-the-fly. ----
        const int tid = threadIdx.x, l = tid & 63, w = tid >> 6;
        const int side = bid >> 5;                   // 0 lab, 1 abn
        const int b2 = bid & 31;
        const int mq = b2 >> 3, nb = b2 & 7;         // 4 m-tiles x 8 n-tiles
        const int em = mq * 32;
        const float* W2  = side ? (W_abn + NF * NF) : (W_lab + NF * NF);
        const float* con = side ? abn_con : lab_con;
        const float* rel = side ? abn_rel : lab_rel;
        const int*   idx = side ? abn_idx : lab_idx;

        f32x16 acc;
        #pragma unroll
        for (int r = 0; r < 16; ++r) acc[r] = 0.f;

        const int e  = em + (l & 31);
        const int kk = ((l >> 5) & 1) * 8;
        const int n  = nb * 32 + (l & 31);
        const float* cp = con + idx[e] * NC;
        const float* rp = rel + e * NC;
        #pragma unroll 4
        for (int k16 = 0; k16 < 12; ++k16) {
            const int k = (w * 12 + k16) * 16 + kk;  // global K offset (incl lane half)
            float4 c0 = *(const float4*)(cp + k);
            float4 c1 = *(const float4*)(cp + k + 4);
            float4 r0 = *(const float4*)(rp + k);
            float4 r1 = *(const float4*)(rp + k + 4);
            float v[8] = {c0.x + r0.x, c0.y + r0.y, c0.z + r0.z, c0.w + r0.w,
                          c1.x + r1.x, c1.y + r1.y, c1.z + r1.z, c1.w + r1.w};
            bf16x8 af;
            #pragma unroll
            for (int j = 0; j < 8; ++j) af[j] = f2bf(v[j]);
            const float* wp = W2 + k * NF + n;       // B col n, rows k..k+7
            bf16x8 bv;
            #pragma unroll
            for (int j = 0; j < 8; ++j) bv[j] = f2bf(wp[j * NF]);
            acc = mfma32(af, bv, acc);
        }
        #pragma unroll
        for (int r = 0; r < 16; ++r) sP[w * 1024 + r * 64 + l] = acc[r];
        __syncthreads();
        float* outp = (float*)(ws + (side ? WS_ABN_CB : WS_LAB_CB));
        const float* bias = side ? b_abn : b_lab;
        #pragma unroll
        for (int q = 0; q < 4; ++q) {
            const int idx2 = q * 256 + tid;
            float v = sP[idx2] + sP[1024 + idx2] + sP[2048 + idx2] + sP[3072 + idx2];
            const int reg = idx2 >> 6, ll = idx2 & 63;
            const int er = (reg & 3) + 8 * (reg >> 2) + 4 * (ll >> 5);
            const int col = nb * 32 + (ll & 31);
            outp[(em + er) * NF + col] = v + bias[col];
        }
    } else if (bid < 112) {
        // ---- sumRel[o][k] = sum over lab edges with org==o of lab_rel[e][k] ----
        const int b2 = bid - 64;
        const int o = b2 / 3, kth = b2 % 3;
        const int k = kth * 256 + threadIdx.x;
        float s = 0.f;
        #pragma unroll 16
        for (int e = 0; e < NE; ++e) {
            const float v = lab_rel[e * NC + k];
            s += (lab_org_idx[e] == o) ? v : 0.f;
        }
        ((float*)(ws + WS_SUMREL))[o * NC + k] = s;
    } else if (bid == 112) {
        // ---- metadata: counts, organ-sorted edge lists, wcnt ----
        __shared__ int cL[NORG], cA[NORG], cC[NROW * NORG];
        __shared__ int goL[NORG + 1], goA[NORG + 1], curL[NORG], curA[NORG];
        const int t = threadIdx.x;
        for (int i = t; i < NROW * NORG; i += 256) cC[i] = 0;
        if (t < NORG) { cL[t] = 0; cA[t] = 0; }
        __syncthreads();
        if (t < NE) {
            atomicAdd(&cL[lab_org_idx[t]], 1);
            atomicAdd(&cA[abn_org_idx[t]], 1);
            atomicAdd(&cC[o2a_abn_idx[t] * NORG + o2a_org_idx[t]], 1);
        }
        __syncthreads();
        if (t == 0) { int s = 0; for (int o = 0; o < NORG; ++o) { goL[o] = s; s += cL[o]; } goL[NORG] = s; }
        if (t == 1) { int s = 0; for (int o = 0; o < NORG; ++o) { goA[o] = s; s += cA[o]; } goA[NORG] = s; }
        __syncthreads();
        if (t < NORG) { curL[t] = goL[t]; curA[t] = goA[t]; }
        __syncthreads();
        if (t < NE) {
            const int ol = lab_org_idx[t], oa = abn_org_idx[t];
            int p = atomicAdd(&curL[ol], 1);
            ((int*)(ws + WS_SRTL))[p] = (lab_idx[t] << 24) | (ol << 16) | t;
            int q = atomicAdd(&curA[oa], 1);
            ((int*)(ws + WS_SRTA))[q] = (abn_idx[t] << 24) | (oa << 16) | t;
        }
        if (t < NORG) {
            ((float*)(ws + WS_INVL))[t] = cL[t] ? 1.f / (float)cL[t] : 0.f;
            ((float*)(ws + WS_INVA))[t] = cA[t] ? 1.f / (float)cA[t] : 0.f;
            ((float*)(ws + WS_MASK))[t] = (cL[t] || cA[t]) ? 1.f : 0.f;
        }
        if (t < NROW) {
            int dega = 0;
            for (int o = 0; o < NORG; ++o) dega += cC[t * NORG + o];
            float inv = 1.f / (float)(dega > 1 ? dega : 1);
            for (int o = 0; o < NORG; ++o)
                ((float*)(ws + WS_WCNT))[t * NORG + o] = (float)cC[t * NORG + o] * inv;
        }
    } else {
        const int gid = (bid - 113) * 256 + threadIdx.x;
        if      (gid <  8192) swz32(W_lab, (short*)(ws + WS_SW_LAB1), gid);
        else if (gid < 16384) swz32(W_abn, (short*)(ws + WS_SW_ABN1), gid - 8192);
        else if (gid < 24576) swz16(W_org, (short*)(ws + WS_SW_ORG),  gid - 16384);
        else                  swz16(W_o2a, (short*)(ws + WS_SW_O2A),  gid - 24576);
    }
}

// ---------------------------------------------------------------------------
// Shared helpers.
// ---------------------------------------------------------------------------
__device__ __forceinline__ void stage_A(const float* __restrict__ X, short* __restrict__ sA, int tid) {
    #pragma unroll
    for (int ss = 0; ss < 8; ++ss) {
        const int s = tid + 256 * ss;
        const int k16 = s >> 7, rt = (s >> 6) & 1, l = s & 63;
        const int row = rt * 32 + (l & 31);
        const int kb = k16 * 16 + ((l >> 5) & 1) * 8;
        *(bf16x8*)(sA + s * 8) = pack_a16(X + row * NF + kb);
    }
}

template <int POST>   // 0: tanh * mask ; 1: plain
__device__ __forceinline__ void gemm_small(
    const float* __restrict__ sIn, const short* __restrict__ Bsw,
    const float* __restrict__ bias, const float* __restrict__ mask,
    float* __restrict__ sOut, int tid) {
    const int l = tid & 63, w = tid >> 6;
    f32x4 acc[4];
    #pragma unroll
    for (int i = 0; i < 4; ++i) { acc[i][0] = 0.f; acc[i][1] = 0.f; acc[i][2] = 0.f; acc[i][3] = 0.f; }
    #pragma unroll 2
    for (int k32 = 0; k32 < 8; ++k32) {
        const float* ap = sIn + (l & 15) * SLD + k32 * 32 + ((l >> 4) & 3) * 8;
        bf16x8 af = pack_a16(ap);
        #pragma unroll
        for (int nt = 0; nt < 4; ++nt) {
            bf16x8 bfv = *(const bf16x8*)(Bsw + ((k32 * 16 + w * 4 + nt) * 64 + l) * 8);
            acc[nt] = mfma16(af, bfv, acc[nt]);
        }
    }
    #pragma unroll
    for (int nt = 0; nt < 4; ++nt) {
        const int col = w * 64 + nt * 16 + (l & 15);
        const float b = bias[col];
        #pragma unroll
        for (int reg = 0; reg < 4; ++reg) {
            const int row = ((l >> 4) & 3) * 4 + reg;
            float v = acc[nt][reg] + b;
            if (POST == 0) v = tanh_fast(v) * mask[row];
            sOut[row * SLD + col] = v;
        }
    }
}

// ---------------------------------------------------------------------------
// addsum body: (16-row A = sumRel, zero-padded to 32) @ D -> WS_ADDSUM raw.
// B read on-the-fly from global D. nb in [0,8). Needs 16 KB scratch (sP).
// Runs on 256 threads.
// ---------------------------------------------------------------------------
__device__ __forceinline__ void addsum_body(const float* __restrict__ D,
                                            char* __restrict__ ws, float* __restrict__ sP,
                                            int nb, int tid) {
    const int l = tid & 63, w = tid >> 6;
    const float* sr = (const float*)(ws + WS_SUMREL);
    f32x16 acc;
    #pragma unroll
    for (int r = 0; r < 16; ++r) acc[r] = 0.f;
    const int row = l & 31;
    const int kk = ((l >> 5) & 1) * 8;
    const int n = nb * 32 + (l & 31);
    const float* cp = sr + row * NC;
    #pragma unroll 4
    for (int k16 = 0; k16 < 12; ++k16) {
        const int k = w * 192 + k16 * 16 + kk;
        bf16x8 af;
        if (row < NORG) {
            af = pack_a16(cp + k);
        } else {
            #pragma unroll
            for (int j = 0; j < 8; ++j) af[j] = 0;
        }
        const float* dp = D + k * NF + n;
        bf16x8 bv;
        #pragma unroll
        for (int j = 0; j < 8; ++j) bv[j] = f2bf(dp[j * NF]);
        acc = mfma32(af, bv, acc);
    }
    #pragma unroll
    for (int r = 0; r < 16; ++r) sP[w * 1024 + r * 64 + l] = acc[r];
    __syncthreads();
    float* outp = (float*)(ws + WS_ADDSUM);
    #pragma unroll
    for (int q = 0; q < 4; ++q) {
        const int idx2 = q * 256 + tid;
        float v = sP[idx2] + sP[1024 + idx2] + sP[2048 + idx2] + sP[3072 + idx2];
        const int reg = idx2 >> 6, ll = idx2 & 63;
        const int er = (reg & 3) + 8 * (reg >> 2) + 4 * (ll >> 5);
        const int col = nb * 32 + (ll & 31);
        if (er < NORG) outp[er * NF + col] = v;
    }
}

// ---------------------------------------------------------------------------
// kg_side v3: 512-thread blocks. Blocks 0..7 addsum riders (first 4 waves);
// blocks 8..1031: one per (bt, side) -- X fetched ONCE per tile (R4 traffic),
// but 8 waves: each wave owns one 32-col B group (32 MFMAs), and the edge
// loop is 256 cols x 2 edge-sublists (64 edges/thread, R7's proven
// boundary-organ LDS combine). LDS 35.5 KB -> 4 blocks/CU x 8 waves =
// 32 waves/CU theoretical. Grid 1024 = one residency round.
// ---------------------------------------------------------------------------
__global__ __launch_bounds__(512, 4) void kg_side(
    const float* __restrict__ lab_feats, const float* __restrict__ abn_feats,
    const float* __restrict__ D, char* __restrict__ ws) {
    __shared__ __align__(16) short sY[NROW * SY];    // 33792 B: A-frags / Y
    __shared__ int sE[NE];
    __shared__ float sOv[2 * NF];                    // 2048 B boundary-organ

    const int tid = threadIdx.x;
    if (blockIdx.x < 8) {                            // addsum riders (256 thr)
        if (tid < 256) addsum_body(D, ws, (float*)sY, blockIdx.x, tid);
        return;
    }
    const int idx = blockIdx.x - 8;
    const int side = idx >> 9;                       // 0 = lab, 1 = abn
    const int bt = idx & 511;

    if (tid < NE) sE[tid] = ((const int*)(ws + (side ? WS_SRTA : WS_SRTL)))[tid];

    const float* X   = (side ? abn_feats : lab_feats) + bt * (NROW * NF);
    const short* Bsw = (const short*)(ws + (side ? WS_SW_ABN1 : WS_SW_LAB1));
    const float* cb  = (const float*)(ws + (side ? WS_ABN_CB : WS_LAB_CB));
    float* rawo = (float*)(ws + (side ? WS_RAWA : WS_RAWL)) + bt * (NORG * NF);

    // full A-tile stage (2048 frags), 512 threads x 4
    #pragma unroll
    for (int ss = 0; ss < 4; ++ss) {
        const int s = tid + 512 * ss;
        const int k16 = s >> 7, rt = (s >> 6) & 1, ll = s & 63;
        const int row = rt * 32 + (ll & 31);
        const int kb = k16 * 16 + ((ll >> 5) & 1) * 8;
        *(bf16x8*)(sY + s * 8) = pack_a16(X + row * NF + kb);
    }
    __syncthreads();

    const int l = tid & 63, w = tid >> 6;            // w in 0..7 = B col group
    f32x16 acc[2];
    #pragma unroll
    for (int i = 0; i < 2; ++i)
        #pragma unroll
        for (int r = 0; r < 16; ++r) acc[i][r] = 0.f;
    #pragma unroll 8
    for (int k16 = 0; k16 < 16; ++k16) {
        bf16x8 a0 = *(const bf16x8*)(sY + ((k16 * 2 + 0) * 64 + l) * 8);
        bf16x8 a1 = *(const bf16x8*)(sY + ((k16 * 2 + 1) * 64 + l) * 8);
        bf16x8 b0 = *(const bf16x8*)(Bsw + ((k16 * 8 + w) * 64 + l) * 8);
        acc[0] = mfma32(a0, b0, acc[0]);
        acc[1] = mfma32(a1, b0, acc[1]);
    }
    __syncthreads();                 // all A-frag reads done; region becomes Y

    {
        const int col = w * 32 + (l & 31);
        #pragma unroll
        for (int rt = 0; rt < 2; ++rt)
            #pragma unroll
            for (int reg = 0; reg < 16; ++reg) {
                const int row = rt * 32 + (reg & 3) + 8 * (reg >> 2) + 4 * (l >> 5);
                sY[row * SY + col] = f2bf(acc[rt][reg]);
            }
    }
    __syncthreads();

    // edge reduction: thread = (edge-half eh, col t); 64 edges each.
    const int eh = tid >> 8;                         // 0 or 1 (wave-uniform)
    const int t = tid & 255;
    const short* yt = sY + t;
    const float* cbt = cb + t;
    const int ob0 = (__builtin_amdgcn_readfirstlane(sE[63]) >> 16) & 255;
    const int ob1 = (__builtin_amdgcn_readfirstlane(sE[64]) >> 16) & 255;
    const bool bshared = (ob0 == ob1);               // organ run crosses e63/e64
    const int ebase = eh * 64;
    float racc = 0.f;
    int curo = (__builtin_amdgcn_readfirstlane(sE[ebase]) >> 16) & 255;
    for (int i0 = 0; i0 < 64; i0 += 8) {
        int   pk8[8];
        float cb8[8], y8[8];
        #pragma unroll
        for (int j = 0; j < 8; ++j) {
            const int pk = __builtin_amdgcn_readfirstlane(sE[ebase + i0 + j]);
            pk8[j] = pk;
            cb8[j] = cbt[(pk & 0xffff) * NF];
            y8[j]  = bf2f(yt[(pk >> 24) * SY]);
        }
        #pragma unroll
        for (int j = 0; j < 8; ++j) {
            const int o = (pk8[j] >> 16) & 255;
            if (o != curo) {             // wave-uniform branch
                if (bshared && curo == ob0) sOv[eh * NF + t] = racc;
                else rawo[curo * NF + t] = racc;
                racc = 0.f; curo = o;
            }
            racc += tanh_fast(y8[j] + cb8[j]);
        }
    }
    if (bshared && curo == ob0) sOv[eh * NF + t] = racc;
    else rawo[curo * NF + t] = racc;

    if (bshared) {                       // block-uniform
        __syncthreads();
        if (tid < NF) rawo[ob0 * NF + tid] = sOv[tid] + sOv[NF + tid];
    }
}

// ---------------------------------------------------------------------------
// kg_back: combine means, organ GEMMs, output add. 512 blocks.
// ---------------------------------------------------------------------------
__global__ __launch_bounds__(256, 4) void kg_back(
    const float* __restrict__ abn_feats, const float* __restrict__ b_org,
    const float* __restrict__ b_o2a, const char* __restrict__ ws,
    float* __restrict__ out) {
    __shared__ __align__(16) float sIn[NORG * SLD];  // 16640 B
    __shared__ __align__(16) float sSt[NORG * SLD];  // 16640 B
    __shared__ float sWc[NROW * NORG];               // 4096 B
    __shared__ float sInvL[NORG], sInvA[NORG], sMsk[NORG];

    const int tid = threadIdx.x;
    const int bt = blockIdx.x;

    if      (tid < NORG)     sInvL[tid]          = ((const float*)(ws + WS_INVL))[tid];
    else if (tid < 2 * NORG) sInvA[tid - NORG]   = ((const float*)(ws + WS_INVA))[tid - NORG];
    else if (tid < 3 * NORG) sMsk[tid - 2 * NORG] = ((const float*)(ws + WS_MASK))[tid - 2 * NORG];
    #pragma unroll
    for (int i = tid; i < NROW * NORG; i += 256)
        sWc[i] = ((const float*)(ws + WS_WCNT))[i];

    const float* rawL = (const float*)(ws + WS_RAWL) + bt * (NORG * NF);
    const float* rawA = (const float*)(ws + WS_RAWA) + bt * (NORG * NF);
    const float* addR = (const float*)(ws + WS_ADDSUM);
    __syncthreads();

    // sIn[o][g] = (rawL+addR)*invL + rawA*invA  (selects guard unwritten organs)
    const int g = tid;
    #pragma unroll
    for (int o = 0; o < NORG; ++o) {
        const float il = sInvL[o], ia = sInvA[o];
        const float vl = (il > 0.f) ? (rawL[o * NF + g] + addR[o * NF + g]) * il : 0.f;
        const float va = (ia > 0.f) ? rawA[o * NF + g] * ia : 0.f;
        sIn[o * SLD + g] = vl + va;
    }
    __syncthreads();

    gemm_small<0>(sIn, (const short*)(ws + WS_SW_ORG), b_org, sMsk, sSt, tid);
    __syncthreads();
    gemm_small<1>(sSt, (const short*)(ws + WS_SW_O2A), b_o2a, nullptr, sIn, tid);
    __syncthreads();

    // out[a][g] = abn_feats[a][g] + sum_o wcnt[a][o]*msg[o][g]
    float mr[NORG];
    #pragma unroll
    for (int o = 0; o < NORG; ++o) mr[o] = sIn[o * SLD + g];
    const float* src = abn_feats + bt * (NROW * NF);
    float* dst = out + bt * (NROW * NF);
    #pragma unroll 8
    for (int a = 0; a < NROW; ++a) {
        float s = src[a * NF + g];
        #pragma unroll
        for (int o = 0; o < NORG; ++o) s += sWc[a * NORG + o] * mr[o];
        dst[a * NF + g] = s;
    }
}

// ---------------------------------------------------------------------------
// Fallback path (ws too small): standalone addsum + single-kernel main.
// ---------------------------------------------------------------------------
__global__ __launch_bounds__(256) void pk_addsum(const float* __restrict__ D,
                                                 char* __restrict__ ws) {
    __shared__ __align__(16) float sP[4 * 1024];
    addsum_body(D, ws, sP, blockIdx.x, threadIdx.x);
}

template <bool LAB>
__device__ __forceinline__ void side_pass(
    const float* __restrict__ X, const short* __restrict__ Bsw,
    const float* __restrict__ cb, const float* __restrict__ addR,
    const float* __restrict__ sInv, const int* __restrict__ sE,
    short* __restrict__ sA, float* __restrict__ sAcc, int tid) {
    __syncthreads();                 // prior users of region done
    stage_A(X, sA, tid);
    __syncthreads();
    const int l = tid & 63, w = tid >> 6;
    f32x16 acc[2][2];
    #pragma unroll
    for (int i = 0; i < 2; ++i)
        #pragma unroll
        for (int j = 0; j < 2; ++j)
            #pragma unroll
            for (int r = 0; r < 16; ++r) acc[i][j][r] = 0.f;
    #pragma unroll 8
    for (int k16 = 0; k16 < 16; ++k16) {
        bf16x8 a0 = *(const bf16x8*)(sA + ((k16 * 2 + 0) * 64 + l) * 8);
        bf16x8 a1 = *(const bf16x8*)(sA + ((k16 * 2 + 1) * 64 + l) * 8);
        bf16x8 b0 = *(const bf16x8*)(Bsw + ((k16 * 8 + 2 * w + 0) * 64 + l) * 8);
        bf16x8 b1 = *(const bf16x8*)(Bsw + ((k16 * 8 + 2 * w + 1) * 64 + l) * 8);
        acc[0][0] = mfma32(a0, b0, acc[0][0]);
        acc[1][0] = mfma32(a1, b0, acc[1][0]);
        acc[0][1] = mfma32(a0, b1, acc[0][1]);
        acc[1][1] = mfma32(a1, b1, acc[1][1]);
    }
    __syncthreads();                 // all sA reads done; region becomes sY
    short* sYs = sA;
    #pragma unroll
    for (int rt = 0; rt < 2; ++rt)
        #pragma unroll
        for (int nt = 0; nt < 2; ++nt) {
            const int col = w * 64 + nt * 32 + (l & 31);
            #pragma unroll
            for (int reg = 0; reg < 16; ++reg) {
                const int row = rt * 32 + (reg & 3) + 8 * (reg >> 2) + 4 * (l >> 5);
                sYs[row * SY + col] = f2bf(acc[rt][nt][reg]);
            }
        }
    __syncthreads();
    const int t = tid;
    if (LAB) {
        #pragma unroll
        for (int o = 0; o < NORG; ++o)
            sAcc[o * SLD + t] = addR[o * NF + t] * sInv[o];
    }
    float racc = 0.f;
    int curo = (sE[0] >> 16) & 255;
    #pragma unroll 4
    for (int i = 0; i < NE; ++i) {
        const int pk = sE[i];
        const int o = (pk >> 16) & 255;
        if (o != curo) {             // wave-uniform branch
            sAcc[curo * SLD + t] += racc * sInv[curo];
            racc = 0.f; curo = o;
        }
        const float yv = bf2f(sYs[(pk >> 24) * SY + t]);
        racc += tanh_fast(yv + cb[(pk & 0xffff) * NF + t]);
    }
    sAcc[curo * SLD + t] += racc * sInv[curo];
}

__global__ __launch_bounds__(256, 2) void kg_main(
    const float* __restrict__ lab_feats, const float* __restrict__ abn_feats,
    const float* __restrict__ b_org, const float* __restrict__ b_o2a,
    const char* __restrict__ ws, float* __restrict__ out) {
    __shared__ __align__(16) short sY[NROW * SY];        // 33792 B; aliases A-frags
    __shared__ __align__(16) float sAcc[NORG * SLD];     // 16640 B; later sMsg
    __shared__ __align__(16) float sSt [NORG * SLD];     // 16640 B
    __shared__ int   sEL[NE], sEA[NE];
    __shared__ float sInvL[NORG], sInvA[NORG], sMsk[NORG];

    const int tid = threadIdx.x;
    const int bt = blockIdx.x;

    if (tid < NE) {
        sEL[tid] = ((const int*)(ws + WS_SRTL))[tid];
        sEA[tid] = ((const int*)(ws + WS_SRTA))[tid];
    } else {
        const int u = tid - NE;
        if      (u < 16) sInvL[u]      = ((const float*)(ws + WS_INVL))[u];
        else if (u < 32) sInvA[u - 16] = ((const float*)(ws + WS_INVA))[u - 16];
        else if (u < 48) sMsk[u - 32]  = ((const float*)(ws + WS_MASK))[u - 32];
    }

    const float* Xl = lab_feats + bt * (NROW * NF);
    const float* Xa = abn_feats + bt * (NROW * NF);
    side_pass<true >(Xl, (const short*)(ws + WS_SW_LAB1),
                     (const float*)(ws + WS_LAB_CB), (const float*)(ws + WS_ADDSUM),
                     sInvL, sEL, sY, sAcc, tid);
    side_pass<false>(Xa, (const short*)(ws + WS_SW_ABN1),
                     (const float*)(ws + WS_ABN_CB), nullptr,
                     sInvA, sEA, sY, sAcc, tid);
    __syncthreads();

    gemm_small<0>(sAcc, (const short*)(ws + WS_SW_ORG), b_org, sMsk, sSt, tid);
    __syncthreads();
    float* sMsg = sAcc;   // alias (input of <1> is sSt)
    gemm_small<1>(sSt, (const short*)(ws + WS_SW_O2A), b_o2a, nullptr, sMsg, tid);
    __syncthreads();

    {
        const int g = tid;
        float mr[NORG];
        #pragma unroll
        for (int o = 0; o < NORG; ++o) mr[o] = sMsg[o * SLD + g];
        const float* src = abn_feats + bt * (NROW * NF);
        float* dst = out + bt * (NROW * NF);
        const float* wc = (const float*)(ws + WS_WCNT);
        #pragma unroll 4
        for (int a = 0; a < NROW; ++a) {
            float s = src[a * NF + g];
            #pragma unroll
            for (int o = 0; o < NORG; ++o) s += wc[a * NORG + o] * mr[o];
            dst[a * NF + g] = s;
        }
    }
}

// ---------------------------------------------------------------------------
extern "C" void kernel_launch(void* const* d_in, const int* in_sizes, int n_in,
                              void* d_out, int out_size, void* d_ws, size_t ws_size,
                              hipStream_t stream) {
    const float* lab_feats   = (const float*)d_in[0];
    const float* abn_feats   = (const float*)d_in[1];
    const float* lab_concept = (const float*)d_in[2];
    const float* abn_concept = (const float*)d_in[3];
    const float* lab_rel     = (const float*)d_in[4];
    const float* abn_rel     = (const float*)d_in[5];
    const float* W_lab       = (const float*)d_in[6];
    const float* b_lab       = (const float*)d_in[7];
    const float* W_abn       = (const float*)d_in[8];
    const float* b_abn       = (const float*)d_in[9];
    const float* W_org       = (const float*)d_in[10];
    const float* b_org       = (const float*)d_in[11];
    const float* D           = (const float*)d_in[12];
    const float* W_o2a       = (const float*)d_in[13];
    const float* b_o2a       = (const float*)d_in[14];
    const int* lab_idx     = (const int*)d_in[16];
    const int* lab_org_idx = (const int*)d_in[17];
    const int* abn_idx     = (const int*)d_in[18];
    const int* abn_org_idx = (const int*)d_in[19];
    const int* o2a_abn_idx = (const int*)d_in[20];
    const int* o2a_org_idx = (const int*)d_in[21];
    char* ws = (char*)d_ws;
    float* out = (float*)d_out;

    pk_pre2<<<241, 256, 0, stream>>>(W_lab, W_abn, W_org, W_o2a, lab_rel,
                                     lab_concept, abn_concept, abn_rel,
                                     b_lab, b_abn,
                                     lab_idx, lab_org_idx, abn_idx, abn_org_idx,
                                     o2a_abn_idx, o2a_org_idx, ws);
    if (ws_size >= (size_t)WS_NEED) {
        kg_side<<<8 + 2 * NBT, 512, 0, stream>>>(lab_feats, abn_feats, D, ws);
        kg_back<<<NBT, 256, 0, stream>>>(abn_feats, b_org, b_o2a, ws, out);
    } else {
        pk_addsum<<<8, 256, 0, stream>>>(D, ws);
        kg_main<<<NBT, 256, 0, stream>>>(lab_feats, abn_feats, b_org, b_o2a, ws, out);
    }
}